// Round 8
// baseline (155.975 us; speedup 1.0000x reference)
//
#include <hip/hip_runtime.h>
#include <math.h>

constexpr int NN  = 4096;   // nodes
constexpr int CC  = 256;    // channels
constexpr int EE0 = 65536;  // edges w/o self loops
constexpr int EE  = 69632;  // EE0 + NN
constexpr int KK  = 2048;   // pooled nodes
constexpr int SL  = 128;    // CSR slot stride (max degree <= 128, verified)

// Self-resetting device state (zero-initialized at module load).
//   g_cnt_i/g_cnt_j: written by k_build, last READ by k_attn -> zeroed by k_rank
//   g_zlog:          written by k_attn,  last READ by k_rank -> zeroed by k_eadj
__device__ int    g_cnt_i[NN];
__device__ int    g_cnt_j[NN];
__device__ double g_zlog[NN];

__device__ __forceinline__ void edge_ij(const int* __restrict__ ei, int e, int& i, int& j) {
    if (e < EE0) { i = ei[e]; j = ei[EE0 + e]; }
    else         { i = e - EE0; j = i; }
}

// ---- k_build: slotted-CSR build with pre-materialized slot data + wv + consts + beta ----
__global__ __launch_bounds__(256) void k_build(const int* __restrict__ ei,
                                               int* lsti_j, int* slot_ij, int* lstj_i,
                                               const float* __restrict__ x,
                                               const float* __restrict__ Wq, const float* __restrict__ bq,
                                               const float* __restrict__ gat_w, const float* __restrict__ gat_b,
                                               double* wv, double* consts, double* beta_node, int EB) {
    const int t = threadIdx.x, g = t >> 6, l = t & 63;
    if ((int)blockIdx.x < EB) {
        int e = blockIdx.x * 256 + t;
        if (e >= EE) return;
        int i, j; edge_ij(ei, e, i, j);
        int si = atomicAdd(&g_cnt_i[i], 1);
        int sj = atomicAdd(&g_cnt_j[j], 1);
        lsti_j[i * SL + si]  = j;
        slot_ij[i * SL + si] = j * SL + sj;
        lstj_i[j * SL + sj]  = i;
        return;
    }
    if ((int)blockIdx.x < EB + CC) {
        int k = blockIdx.x - EB;
        double s = (double)Wq[k * CC + t] * (double)gat_w[t];
        #pragma unroll
        for (int d = 32; d > 0; d >>= 1) s += __shfl_down(s, d, 64);
        __shared__ double red[4];
        if (l == 0) red[g] = s;
        __syncthreads();
        if (t == 0) wv[k] = red[0] + red[1] + red[2] + red[3];
        if (k == 0 && t == 0) {
            double cb = 0.0;
            for (int q = 0; q < CC; ++q) cb += (double)bq[q] * (double)gat_w[q];
            consts[0] = cb + (double)gat_b[0];
        }
        return;
    }
    // beta: 4 nodes per block, one wave each
    int m = (blockIdx.x - EB - CC) * 4 + g;
    const float* gw2 = gat_w + CC;
    float4 v = ((const float4*)(x + (size_t)m * CC))[l];
    double s = (double)v.x * (double)gw2[4 * l]     + (double)v.y * (double)gw2[4 * l + 1]
             + (double)v.z * (double)gw2[4 * l + 2] + (double)v.w * (double)gw2[4 * l + 3];
    #pragma unroll
    for (int d = 32; d > 0; d >>= 1) s += __shfl_down(s, d, 64);
    if (l == 0) beta_node[m] = s;
}

// ---- k_attn: wave-per-node (no LDS/sync). Snapshots deg_i/deg_j to ws for k_eadj ----
__global__ __launch_bounds__(256) void k_attn(const float* __restrict__ x,
                                              const int* __restrict__ lsti_j,
                                              const int* __restrict__ slot_ij,
                                              const int* __restrict__ lstj_i,
                                              const double* __restrict__ wv, const double* __restrict__ beta_node,
                                              const double* __restrict__ consts,
                                              const float* __restrict__ le1_w, const float* __restrict__ le1_b,
                                              const float* __restrict__ le2_w,
                                              const float* __restrict__ le3_w, const float* __restrict__ le3_b,
                                              float* __restrict__ sval_i, float* __restrict__ svalj,
                                              float* __restrict__ out32,
                                              int* __restrict__ deg_i, int* __restrict__ deg_j) {
    const int n = (blockIdx.x << 2) + (threadIdx.x >> 6);   // one wave per node
    const int l = threadIdx.x & 63;
    const int base = n * SL;
    const int deg = g_cnt_i[n];
    const int cj  = g_cnt_j[n];
    if (l == 0) { deg_i[n] = deg; deg_j[n] = cj; }          // ws snapshot for k_eadj

    int j0 = 0, j1 = 0;
    double b0 = 0.0, b1 = 0.0;
    if (l < deg)      { j0 = lsti_j[base + l];      b0 = beta_node[j0]; }
    if (l + 64 < deg) { j1 = lsti_j[base + l + 64]; b1 = beta_node[j1]; }

    // ---- pass A: elementwise max over neighbor rows ----
    float4 mx = make_float4(-INFINITY, -INFINITY, -INFINITY, -INFINITY);
    for (int p4 = 0; p4 < deg; p4 += 4) {
        {   int p = p4;
            int jp = __shfl(p < 64 ? j0 : j1, p & 63, 64);
            float4 v = ((const float4*)(x + (size_t)jp * CC))[l];
            mx.x = fmaxf(mx.x, v.x); mx.y = fmaxf(mx.y, v.y);
            mx.z = fmaxf(mx.z, v.z); mx.w = fmaxf(mx.w, v.w);
        }
        if (p4 + 1 < deg) { int p = p4 + 1;
            int jp = __shfl(p < 64 ? j0 : j1, p & 63, 64);
            float4 v = ((const float4*)(x + (size_t)jp * CC))[l];
            mx.x = fmaxf(mx.x, v.x); mx.y = fmaxf(mx.y, v.y);
            mx.z = fmaxf(mx.z, v.z); mx.w = fmaxf(mx.w, v.w);
        }
        if (p4 + 2 < deg) { int p = p4 + 2;
            int jp = __shfl(p < 64 ? j0 : j1, p & 63, 64);
            float4 v = ((const float4*)(x + (size_t)jp * CC))[l];
            mx.x = fmaxf(mx.x, v.x); mx.y = fmaxf(mx.y, v.y);
            mx.z = fmaxf(mx.z, v.z); mx.w = fmaxf(mx.w, v.w);
        }
        if (p4 + 3 < deg) { int p = p4 + 3;
            int jp = __shfl(p < 64 ? j0 : j1, p & 63, 64);
            float4 v = ((const float4*)(x + (size_t)jp * CC))[l];
            mx.x = fmaxf(mx.x, v.x); mx.y = fmaxf(mx.y, v.y);
            mx.z = fmaxf(mx.z, v.z); mx.w = fmaxf(mx.w, v.w);
        }
    }

    // alpha = Xq_max . wv
    double al = (double)mx.x * wv[4 * l]     + (double)mx.y * wv[4 * l + 1]
              + (double)mx.z * wv[4 * l + 2] + (double)mx.w * wv[4 * l + 3];
    #pragma unroll
    for (int d = 32; d > 0; d >>= 1) al += __shfl_down(al, d, 64);
    double an = __shfl(al, 0, 64) + consts[0];

    // ---- per-edge scores ----
    double s0 = 0.0, s1 = 0.0;
    if (l < deg)      { double v = an + b0; s0 = v > 0.0 ? v : 0.2 * v; }
    if (l + 64 < deg) { double v = an + b1; s1 = v > 0.0 ? v : 0.2 * v; }
    double mm = -1e300;
    if (l < deg)      mm = fmax(mm, s0);
    if (l + 64 < deg) mm = fmax(mm, s1);
    #pragma unroll
    for (int d = 32; d > 0; d >>= 1) mm = fmax(mm, __shfl_xor(mm, d, 64));
    double z = 0.0;
    if (l < deg)      z += exp(s0 - mm);
    if (l + 64 < deg) z += exp(s1 - mm);
    #pragma unroll
    for (int d = 32; d > 0; d >>= 1) z += __shfl_xor(z, d, 64);
    double inv = 1.0 / z;

    double sc0 = 0.0, sc1 = 0.0;
    if (l < deg) {
        sc0 = exp(s0 - mm) * inv;
        float scf = (float)sc0;
        sval_i[base + l] = scf;
        svalj[slot_ij[base + l]] = scf;
    }
    if (l + 64 < deg) {
        sc1 = exp(s1 - mm) * inv;
        float scf = (float)sc1;
        sval_i[base + l + 64] = scf;
        svalj[slot_ij[base + l + 64]] = scf;
    }

    // ---- pass B: out = sum score * x[j]; 4 accumulator groups by p&3 ----
    double A0x = 0, A0y = 0, A0z = 0, A0w = 0;
    double A1x = 0, A1y = 0, A1z = 0, A1w = 0;
    double A2x = 0, A2y = 0, A2z = 0, A2w = 0;
    double A3x = 0, A3y = 0, A3z = 0, A3w = 0;
    for (int p4 = 0; p4 < deg; p4 += 4) {
        {   int p = p4;
            double sc = __shfl(p < 64 ? sc0 : sc1, p & 63, 64);
            int jp = __shfl(p < 64 ? j0 : j1, p & 63, 64);
            float4 v = ((const float4*)(x + (size_t)jp * CC))[l];
            A0x += sc * (double)v.x; A0y += sc * (double)v.y;
            A0z += sc * (double)v.z; A0w += sc * (double)v.w;
        }
        if (p4 + 1 < deg) { int p = p4 + 1;
            double sc = __shfl(p < 64 ? sc0 : sc1, p & 63, 64);
            int jp = __shfl(p < 64 ? j0 : j1, p & 63, 64);
            float4 v = ((const float4*)(x + (size_t)jp * CC))[l];
            A1x += sc * (double)v.x; A1y += sc * (double)v.y;
            A1z += sc * (double)v.z; A1w += sc * (double)v.w;
        }
        if (p4 + 2 < deg) { int p = p4 + 2;
            double sc = __shfl(p < 64 ? sc0 : sc1, p & 63, 64);
            int jp = __shfl(p < 64 ? j0 : j1, p & 63, 64);
            float4 v = ((const float4*)(x + (size_t)jp * CC))[l];
            A2x += sc * (double)v.x; A2y += sc * (double)v.y;
            A2z += sc * (double)v.z; A2w += sc * (double)v.w;
        }
        if (p4 + 3 < deg) { int p = p4 + 3;
            double sc = __shfl(p < 64 ? sc0 : sc1, p & 63, 64);
            int jp = __shfl(p < 64 ? j0 : j1, p & 63, 64);
            float4 v = ((const float4*)(x + (size_t)jp * CC))[l];
            A3x += sc * (double)v.x; A3y += sc * (double)v.y;
            A3z += sc * (double)v.z; A3w += sc * (double)v.w;
        }
    }
    double o0 = A0x + A1x + A2x + A3x;
    double o1 = A0y + A1y + A2y + A3y;
    double o2 = A0z + A1z + A2z + A3z;
    double o3 = A0w + A1w + A2w + A3w;

    float4 ov; ov.x = (float)o0; ov.y = (float)o1; ov.z = (float)o2; ov.w = (float)o3;
    ((float4*)(out32 + (size_t)n * CC))[l] = ov;

    float4 w1 = ((const float4*)le1_w)[l];
    float4 w2 = ((const float4*)le2_w)[l];
    float4 w3 = ((const float4*)le3_w)[l];
    double t1 = o0 * (double)w1.x + o1 * (double)w1.y + o2 * (double)w1.z + o3 * (double)w1.w;
    double t2 = o0 * (double)w2.x + o1 * (double)w2.y + o2 * (double)w2.z + o3 * (double)w2.w;
    double t3 = o0 * (double)w3.x + o1 * (double)w3.y + o2 * (double)w3.z + o3 * (double)w3.w;
    #pragma unroll
    for (int d = 32; d > 0; d >>= 1) {
        t1 += __shfl_down(t1, d, 64);
        t2 += __shfl_down(t2, d, 64);
        t3 += __shfl_down(t3, d, 64);
    }
    double a64n;
    if (l == 0) {
        double a64_ = t1 + (double)le1_b[0];
        double b64_ = t2;
        double l3v_ = t3 + (double)le3_b[0];
        atomicAdd(&g_zlog[n], l3v_ - (double)deg * b64_);
        a64n = a64_;
    }
    a64n = __shfl(a64n, 0, 64);

    int jb = n * SL;
    for (int p = l; p < cj; p += 64) {
        atomicAdd(&g_zlog[lstj_i[jb + p]], a64n);
    }
}

// ---- k_rank: 1024 blocks x 4 nodes; zlog staged ONCE in LDS, shared by 4 counts.
//      Per-node count expression and shuffle tree bit-identical to r7.
//      3 barriers/block, 4 blocks/CU (r6 lesson). Folds g_cnt reset. ----
__global__ __launch_bounds__(256) void k_rank(const float* __restrict__ out32,
                                              int* __restrict__ perm, int* __restrict__ n_idx,
                                              float* __restrict__ xout, float* __restrict__ operm) {
    __shared__ double zl[NN];          // 32 KB
    __shared__ int red[4][4];          // [wave][node]
    __shared__ int rr4[4];
    const int b = blockIdx.x, t = threadIdx.x;

    if (t < 4) { g_cnt_i[b * 4 + t] = 0; g_cnt_j[b * 4 + t] = 0; }   // self-reset
    for (int u = t; u < NN; u += 256) zl[u] = g_zlog[u];
    __syncthreads();

    const int n0 = b * 4;
    double zn0 = zl[n0], zn1 = zl[n0 + 1], zn2 = zl[n0 + 2], zn3 = zl[n0 + 3];
    int c0 = 0, c1 = 0, c2 = 0, c3 = 0;
    #pragma unroll
    for (int u = 0; u < NN / 256; ++u) {
        int m = t + u * 256;
        double zm = zl[m];                         // one load feeds 4 counters
        c0 += ((zm > zn0) || (zm == zn0 && m < n0    )) ? 1 : 0;
        c1 += ((zm > zn1) || (zm == zn1 && m < n0 + 1)) ? 1 : 0;
        c2 += ((zm > zn2) || (zm == zn2 && m < n0 + 2)) ? 1 : 0;
        c3 += ((zm > zn3) || (zm == zn3 && m < n0 + 3)) ? 1 : 0;
    }
    #pragma unroll
    for (int d = 32; d > 0; d >>= 1) {
        c0 += __shfl_down(c0, d, 64);
        c1 += __shfl_down(c1, d, 64);
        c2 += __shfl_down(c2, d, 64);
        c3 += __shfl_down(c3, d, 64);
    }
    if ((t & 63) == 0) {
        int g = t >> 6;
        red[g][0] = c0; red[g][1] = c1; red[g][2] = c2; red[g][3] = c3;
    }
    __syncthreads();
    if (t < 4) {
        int r = red[0][t] + red[1][t] + red[2][t] + red[3][t];
        rr4[t] = r;
        int n = n0 + t;
        if (r < KK) {
            perm[r] = n;
            n_idx[n] = r;
            operm[r] = (float)n;
        } else {
            n_idx[n] = -1;
        }
    }
    __syncthreads();
    #pragma unroll
    for (int v = 0; v < 4; ++v) {
        int r = rr4[v];
        if (r < KK) {
            double zn = zl[n0 + v];
            double fit = 1.0 / (1.0 + exp(-zn));
            xout[(size_t)r * CC + t] = (float)((double)out32[(size_t)(n0 + v) * CC + t] * fit);
        }
    }
}

// ---- k_eadj: row (j,s1) pairs staged in LDS once; 16 groups x 16 lanes inner
//      (cj ~ 17 -> near-full lane utilization); zeroes g_zlog for next replay ----
__global__ __launch_bounds__(256) void k_eadj(const int* __restrict__ deg_i, const int* __restrict__ lsti_j,
                                              const float* __restrict__ sval_i,
                                              const int* __restrict__ deg_j, const int* __restrict__ lstj_i,
                                              const float* __restrict__ svalj,
                                              const int* __restrict__ n_idx,
                                              const int* __restrict__ perm,
                                              float* __restrict__ Ead) {
    __shared__ float row[KK];
    __shared__ int   sjj[SL];
    __shared__ float ssv[SL];
    int r = blockIdx.x, t = threadIdx.x;

    // reset zlog for next replay (no reader of g_zlog in this kernel)
    if (r < 512 && t < 8) g_zlog[r * 8 + t] = 0.0;

    float4 z4 = make_float4(0.f, 0.f, 0.f, 0.f);
    for (int c = t; c < KK / 4; c += 256) ((float4*)row)[c] = z4;
    int n = perm[r];
    int deg = deg_i[n];
    int base = n * SL;
    if (t < deg) { sjj[t] = lsti_j[base + t]; ssv[t] = sval_i[base + t]; }
    __syncthreads();
    int grp = t >> 4, lane = t & 15;          // 16 groups of 16 lanes
    for (int p = grp; p < deg; p += 16) {
        int j = sjj[p];
        float s1 = ssv[p];
        int cj = deg_j[j], jb = j * SL;
        for (int q = lane; q < cj; q += 16) {
            int c = n_idx[lstj_i[jb + q]];
            if (c >= 0) atomicAdd(&row[c], s1 * svalj[jb + q]);
        }
    }
    __syncthreads();
    float* __restrict__ erow = Ead + (size_t)r * KK;
    for (int c4 = t; c4 < KK / 4; c4 += 256) {
        float4 v = ((float4*)row)[c4];
        int base4 = c4 * 4;
        int dr = r - base4;
        if (dr >= 0 && dr < 4) ((float*)&v)[dr] = 1.0f;
        ((float4*)erow)[c4] = v;
    }
}

// ============================ host ============================
extern "C" void kernel_launch(void* const* d_in, const int* in_sizes, int n_in,
                              void* d_out, int out_size, void* d_ws, size_t ws_size,
                              hipStream_t stream) {
    const float* x     = (const float*)d_in[0];
    const int*   ei    = (const int*)d_in[1];
    const float* Wq    = (const float*)d_in[2];
    const float* bq    = (const float*)d_in[3];
    const float* gat_w = (const float*)d_in[4];
    const float* gat_b = (const float*)d_in[5];
    const float* le1_w = (const float*)d_in[6];
    const float* le1_b = (const float*)d_in[7];
    const float* le2_w = (const float*)d_in[8];
    const float* le3_w = (const float*)d_in[9];
    const float* le3_b = (const float*)d_in[10];

    float* xout  = (float*)d_out;          // [K, C]
    float* Ead   = xout + (size_t)KK * CC; // [K, K]
    float* operm = Ead + (size_t)KK * KK;  // [K]

    char* w = (char*)d_ws;
    auto alloc = [&](size_t bytes) -> void* {
        void* p = (void*)w;
        w += (bytes + 255) & ~(size_t)255;
        return p;
    };
    float*  out32  = (float*)alloc((size_t)NN * CC * 4);
    double* beta_node = (double*)alloc(NN * 8);
    double* wv     = (double*)alloc(CC * 8);
    double* consts = (double*)alloc(64);
    int*   lsti_j  = (int*)alloc((size_t)NN * SL * 4);
    int*   slot_ij = (int*)alloc((size_t)NN * SL * 4);
    int*   lstj_i  = (int*)alloc((size_t)NN * SL * 4);
    float* sval_i  = (float*)alloc((size_t)NN * SL * 4);
    float* svalj   = (float*)alloc((size_t)NN * SL * 4);
    int*   n_idx   = (int*)alloc(NN * 4);
    int*   perm    = (int*)alloc(KK * 4);
    int*   deg_i   = (int*)alloc(NN * 4);
    int*   deg_j   = (int*)alloc(NN * 4);

    const int EB = (EE + 255) / 256;  // 272

    k_build<<<EB + CC + NN / 4, 256, 0, stream>>>(ei, lsti_j, slot_ij, lstj_i, x,
                                                  Wq, bq, gat_w, gat_b, wv, consts, beta_node, EB);
    k_attn<<<NN / 4, 256, 0, stream>>>(x, lsti_j, slot_ij, lstj_i,
                                       wv, beta_node, consts,
                                       le1_w, le1_b, le2_w, le3_w, le3_b,
                                       sval_i, svalj, out32, deg_i, deg_j);
    k_rank<<<NN / 4, 256, 0, stream>>>(out32, perm, n_idx, xout, operm);
    k_eadj<<<KK, 256, 0, stream>>>(deg_i, lsti_j, sval_i, deg_j, lstj_i, svalj,
                                   n_idx, perm, Ead);
}

// Round 10
// 139.330 us; speedup vs baseline: 1.1195x; 1.1195x over previous
//
#include <hip/hip_runtime.h>
#include <math.h>

constexpr int NN  = 4096;   // nodes
constexpr int CC  = 256;    // channels
constexpr int EE0 = 65536;  // edges w/o self loops
constexpr int EE  = 69632;  // EE0 + NN
constexpr int KK  = 2048;   // pooled nodes
constexpr int SL  = 128;    // CSR slot stride (max degree <= 128, verified)

// Self-resetting device state (zero-initialized at module load).
// Reset protocol (race-free via kernel boundaries + last-reader analysis):
//   g_cnt_i/g_cnt_j: written by k_build, last READ by k_attn -> zeroed by k_rank (block n)
//   g_zlog:          written by k_attn,  last READ by k_rank -> zeroed by k_eadj
__device__ int    g_cnt_i[NN];
__device__ int    g_cnt_j[NN];
__device__ double g_zlog[NN];

__device__ __forceinline__ void edge_ij(const int* __restrict__ ei, int e, int& i, int& j) {
    if (e < EE0) { i = ei[e]; j = ei[EE0 + e]; }
    else         { i = e - EE0; j = i; }
}

// ---- k_build: slotted-CSR build with pre-materialized slot data + wv + consts + beta ----
__global__ __launch_bounds__(256) void k_build(const int* __restrict__ ei,
                                               int* lsti_j, int* slot_ij, int* lstj_i,
                                               const float* __restrict__ x,
                                               const float* __restrict__ Wq, const float* __restrict__ bq,
                                               const float* __restrict__ gat_w, const float* __restrict__ gat_b,
                                               double* wv, double* consts, double* beta_node, int EB) {
    const int t = threadIdx.x, g = t >> 6, l = t & 63;
    if ((int)blockIdx.x < EB) {
        int e = blockIdx.x * 256 + t;
        if (e >= EE) return;
        int i, j; edge_ij(ei, e, i, j);
        int si = atomicAdd(&g_cnt_i[i], 1);
        int sj = atomicAdd(&g_cnt_j[j], 1);
        lsti_j[i * SL + si]  = j;
        slot_ij[i * SL + si] = j * SL + sj;
        lstj_i[j * SL + sj]  = i;
        return;
    }
    if ((int)blockIdx.x < EB + CC) {
        int k = blockIdx.x - EB;
        double s = (double)Wq[k * CC + t] * (double)gat_w[t];
        #pragma unroll
        for (int d = 32; d > 0; d >>= 1) s += __shfl_down(s, d, 64);
        __shared__ double red[4];
        if (l == 0) red[g] = s;
        __syncthreads();
        if (t == 0) wv[k] = red[0] + red[1] + red[2] + red[3];
        if (k == 0 && t == 0) {
            double cb = 0.0;
            for (int q = 0; q < CC; ++q) cb += (double)bq[q] * (double)gat_w[q];
            consts[0] = cb + (double)gat_b[0];
        }
        return;
    }
    // beta: 4 nodes per block, one wave each
    int m = (blockIdx.x - EB - CC) * 4 + g;
    const float* gw2 = gat_w + CC;
    float4 v = ((const float4*)(x + (size_t)m * CC))[l];
    double s = (double)v.x * (double)gw2[4 * l]     + (double)v.y * (double)gw2[4 * l + 1]
             + (double)v.z * (double)gw2[4 * l + 2] + (double)v.w * (double)gw2[4 * l + 3];
    #pragma unroll
    for (int d = 32; d > 0; d >>= 1) s += __shfl_down(s, d, 64);
    if (l == 0) beta_node[m] = s;
}

// ---- k_attn: wave-per-node (no LDS/sync). Snapshots deg_i/deg_j to ws for k_eadj ----
__global__ __launch_bounds__(256) void k_attn(const float* __restrict__ x,
                                              const int* __restrict__ lsti_j,
                                              const int* __restrict__ slot_ij,
                                              const int* __restrict__ lstj_i,
                                              const double* __restrict__ wv, const double* __restrict__ beta_node,
                                              const double* __restrict__ consts,
                                              const float* __restrict__ le1_w, const float* __restrict__ le1_b,
                                              const float* __restrict__ le2_w,
                                              const float* __restrict__ le3_w, const float* __restrict__ le3_b,
                                              float* __restrict__ sval_i, float* __restrict__ svalj,
                                              float* __restrict__ out32,
                                              int* __restrict__ deg_i, int* __restrict__ deg_j) {
    const int n = (blockIdx.x << 2) + (threadIdx.x >> 6);   // one wave per node
    const int l = threadIdx.x & 63;
    const int base = n * SL;
    const int deg = g_cnt_i[n];
    const int cj  = g_cnt_j[n];
    if (l == 0) { deg_i[n] = deg; deg_j[n] = cj; }          // ws snapshot for k_eadj

    int j0 = 0, j1 = 0;
    double b0 = 0.0, b1 = 0.0;
    if (l < deg)      { j0 = lsti_j[base + l];      b0 = beta_node[j0]; }
    if (l + 64 < deg) { j1 = lsti_j[base + l + 64]; b1 = beta_node[j1]; }

    // ---- pass A: elementwise max over neighbor rows ----
    float4 mx = make_float4(-INFINITY, -INFINITY, -INFINITY, -INFINITY);
    for (int p4 = 0; p4 < deg; p4 += 4) {
        {   int p = p4;
            int jp = __shfl(p < 64 ? j0 : j1, p & 63, 64);
            float4 v = ((const float4*)(x + (size_t)jp * CC))[l];
            mx.x = fmaxf(mx.x, v.x); mx.y = fmaxf(mx.y, v.y);
            mx.z = fmaxf(mx.z, v.z); mx.w = fmaxf(mx.w, v.w);
        }
        if (p4 + 1 < deg) { int p = p4 + 1;
            int jp = __shfl(p < 64 ? j0 : j1, p & 63, 64);
            float4 v = ((const float4*)(x + (size_t)jp * CC))[l];
            mx.x = fmaxf(mx.x, v.x); mx.y = fmaxf(mx.y, v.y);
            mx.z = fmaxf(mx.z, v.z); mx.w = fmaxf(mx.w, v.w);
        }
        if (p4 + 2 < deg) { int p = p4 + 2;
            int jp = __shfl(p < 64 ? j0 : j1, p & 63, 64);
            float4 v = ((const float4*)(x + (size_t)jp * CC))[l];
            mx.x = fmaxf(mx.x, v.x); mx.y = fmaxf(mx.y, v.y);
            mx.z = fmaxf(mx.z, v.z); mx.w = fmaxf(mx.w, v.w);
        }
        if (p4 + 3 < deg) { int p = p4 + 3;
            int jp = __shfl(p < 64 ? j0 : j1, p & 63, 64);
            float4 v = ((const float4*)(x + (size_t)jp * CC))[l];
            mx.x = fmaxf(mx.x, v.x); mx.y = fmaxf(mx.y, v.y);
            mx.z = fmaxf(mx.z, v.z); mx.w = fmaxf(mx.w, v.w);
        }
    }

    // alpha = Xq_max . wv
    double al = (double)mx.x * wv[4 * l]     + (double)mx.y * wv[4 * l + 1]
              + (double)mx.z * wv[4 * l + 2] + (double)mx.w * wv[4 * l + 3];
    #pragma unroll
    for (int d = 32; d > 0; d >>= 1) al += __shfl_down(al, d, 64);
    double an = __shfl(al, 0, 64) + consts[0];

    // ---- per-edge scores: leaky relu, then m/z butterfly reductions ----
    double s0 = 0.0, s1 = 0.0;
    if (l < deg)      { double v = an + b0; s0 = v > 0.0 ? v : 0.2 * v; }
    if (l + 64 < deg) { double v = an + b1; s1 = v > 0.0 ? v : 0.2 * v; }
    double mm = -1e300;
    if (l < deg)      mm = fmax(mm, s0);
    if (l + 64 < deg) mm = fmax(mm, s1);
    #pragma unroll
    for (int d = 32; d > 0; d >>= 1) mm = fmax(mm, __shfl_xor(mm, d, 64));
    double z = 0.0;
    if (l < deg)      z += exp(s0 - mm);
    if (l + 64 < deg) z += exp(s1 - mm);
    #pragma unroll
    for (int d = 32; d > 0; d >>= 1) z += __shfl_xor(z, d, 64);
    double inv = 1.0 / z;

    double sc0 = 0.0, sc1 = 0.0;
    if (l < deg) {
        sc0 = exp(s0 - mm) * inv;
        float scf = (float)sc0;
        sval_i[base + l] = scf;
        svalj[slot_ij[base + l]] = scf;
    }
    if (l + 64 < deg) {
        sc1 = exp(s1 - mm) * inv;
        float scf = (float)sc1;
        sval_i[base + l + 64] = scf;
        svalj[slot_ij[base + l + 64]] = scf;
    }

    // ---- pass B: out = sum score * x[j]; 4 accumulator groups by p&3 ----
    double A0x = 0, A0y = 0, A0z = 0, A0w = 0;
    double A1x = 0, A1y = 0, A1z = 0, A1w = 0;
    double A2x = 0, A2y = 0, A2z = 0, A2w = 0;
    double A3x = 0, A3y = 0, A3z = 0, A3w = 0;
    for (int p4 = 0; p4 < deg; p4 += 4) {
        {   int p = p4;
            double sc = __shfl(p < 64 ? sc0 : sc1, p & 63, 64);
            int jp = __shfl(p < 64 ? j0 : j1, p & 63, 64);
            float4 v = ((const float4*)(x + (size_t)jp * CC))[l];
            A0x += sc * (double)v.x; A0y += sc * (double)v.y;
            A0z += sc * (double)v.z; A0w += sc * (double)v.w;
        }
        if (p4 + 1 < deg) { int p = p4 + 1;
            double sc = __shfl(p < 64 ? sc0 : sc1, p & 63, 64);
            int jp = __shfl(p < 64 ? j0 : j1, p & 63, 64);
            float4 v = ((const float4*)(x + (size_t)jp * CC))[l];
            A1x += sc * (double)v.x; A1y += sc * (double)v.y;
            A1z += sc * (double)v.z; A1w += sc * (double)v.w;
        }
        if (p4 + 2 < deg) { int p = p4 + 2;
            double sc = __shfl(p < 64 ? sc0 : sc1, p & 63, 64);
            int jp = __shfl(p < 64 ? j0 : j1, p & 63, 64);
            float4 v = ((const float4*)(x + (size_t)jp * CC))[l];
            A2x += sc * (double)v.x; A2y += sc * (double)v.y;
            A2z += sc * (double)v.z; A2w += sc * (double)v.w;
        }
        if (p4 + 3 < deg) { int p = p4 + 3;
            double sc = __shfl(p < 64 ? sc0 : sc1, p & 63, 64);
            int jp = __shfl(p < 64 ? j0 : j1, p & 63, 64);
            float4 v = ((const float4*)(x + (size_t)jp * CC))[l];
            A3x += sc * (double)v.x; A3y += sc * (double)v.y;
            A3z += sc * (double)v.z; A3w += sc * (double)v.w;
        }
    }
    double o0 = A0x + A1x + A2x + A3x;
    double o1 = A0y + A1y + A2y + A3y;
    double o2 = A0z + A1z + A2z + A3z;
    double o3 = A0w + A1w + A2w + A3w;

    float4 ov; ov.x = (float)o0; ov.y = (float)o1; ov.z = (float)o2; ov.w = (float)o3;
    ((float4*)(out32 + (size_t)n * CC))[l] = ov;

    float4 w1 = ((const float4*)le1_w)[l];
    float4 w2 = ((const float4*)le2_w)[l];
    float4 w3 = ((const float4*)le3_w)[l];
    double t1 = o0 * (double)w1.x + o1 * (double)w1.y + o2 * (double)w1.z + o3 * (double)w1.w;
    double t2 = o0 * (double)w2.x + o1 * (double)w2.y + o2 * (double)w2.z + o3 * (double)w2.w;
    double t3 = o0 * (double)w3.x + o1 * (double)w3.y + o2 * (double)w3.z + o3 * (double)w3.w;
    #pragma unroll
    for (int d = 32; d > 0; d >>= 1) {
        t1 += __shfl_down(t1, d, 64);
        t2 += __shfl_down(t2, d, 64);
        t3 += __shfl_down(t3, d, 64);
    }
    double a64n;
    if (l == 0) {
        double a64_ = t1 + (double)le1_b[0];
        double b64_ = t2;
        double l3v_ = t3 + (double)le3_b[0];
        atomicAdd(&g_zlog[n], l3v_ - (double)deg * b64_);
        a64n = a64_;
    }
    a64n = __shfl(a64n, 0, 64);

    // zlog push: zlog[i] += a64[n] over CSR-j slots of n
    int jb = n * SL;
    for (int p = l; p < cj; p += 64) {
        atomicAdd(&g_zlog[lstj_i[jb + p]], a64n);
    }
}

// ---- k_rank: r7 shape (4096 independent blocks), reads g_zlog from L2.
//      Folds the g_cnt reset (thread 0 of block n; attn is the last cnt reader). ----
__global__ __launch_bounds__(256) void k_rank(const float* __restrict__ out32,
                                              int* __restrict__ perm, int* __restrict__ n_idx,
                                              float* __restrict__ xout, float* __restrict__ operm) {
    int n = blockIdx.x, t = threadIdx.x;
    if (t == 0) { g_cnt_i[n] = 0; g_cnt_j[n] = 0; }   // self-reset for next replay
    double zn = g_zlog[n];
    int cnt = 0;
    #pragma unroll
    for (int u = 0; u < NN / 256; ++u) {
        int m = t + u * 256;
        double zm = g_zlog[m];
        cnt += ((zm > zn) || (zm == zn && m < n)) ? 1 : 0;
    }
    #pragma unroll
    for (int d = 32; d > 0; d >>= 1) cnt += __shfl_down(cnt, d, 64);
    __shared__ int red[4];
    __shared__ int rr;
    if ((t & 63) == 0) red[t >> 6] = cnt;
    __syncthreads();
    if (t == 0) {
        int r = red[0] + red[1] + red[2] + red[3];
        rr = r;
        if (r < KK) {
            perm[r] = n;
            n_idx[n] = r;
            operm[r] = (float)n;
        } else {
            n_idx[n] = -1;
        }
    }
    __syncthreads();
    int r = rr;
    if (r < KK) {
        double fit = 1.0 / (1.0 + exp(-zn));
        xout[(size_t)r * CC + t] = (float)((double)out32[(size_t)n * CC + t] * fit);
    }
}

// ---- k_eadj: Eadj rows in 8KB LDS; reads deg snapshots from ws; zeroes g_zlog ----
__global__ __launch_bounds__(256) void k_eadj(const int* __restrict__ deg_i, const int* __restrict__ lsti_j,
                                              const float* __restrict__ sval_i,
                                              const int* __restrict__ deg_j, const int* __restrict__ lstj_i,
                                              const float* __restrict__ svalj,
                                              const int* __restrict__ n_idx,
                                              const int* __restrict__ perm,
                                              float* __restrict__ Ead) {
    __shared__ float row[KK];
    int r = blockIdx.x, t = threadIdx.x;

    // reset zlog for next replay (no reader of g_zlog in this kernel)
    if (r < 512 && t < 8) g_zlog[r * 8 + t] = 0.0;

    float4 z4 = make_float4(0.f, 0.f, 0.f, 0.f);
    for (int c = t; c < KK / 4; c += 256) ((float4*)row)[c] = z4;
    __syncthreads();
    int n = perm[r];
    int deg = deg_i[n];
    int base = n * SL;
    int grp = t >> 5, lane = t & 31;
    for (int p = grp; p < deg; p += 8) {
        int j = lsti_j[base + p];
        float s1 = sval_i[base + p];
        int cj = deg_j[j], jb = j * SL;
        for (int q = lane; q < cj; q += 32) {
            int c = n_idx[lstj_i[jb + q]];
            if (c >= 0) atomicAdd(&row[c], s1 * svalj[jb + q]);
        }
    }
    __syncthreads();
    float* __restrict__ erow = Ead + (size_t)r * KK;
    for (int c4 = t; c4 < KK / 4; c4 += 256) {
        float4 v = ((float4*)row)[c4];
        int base4 = c4 * 4;
        int dr = r - base4;
        if (dr >= 0 && dr < 4) ((float*)&v)[dr] = 1.0f;
        ((float4*)erow)[c4] = v;
    }
}

// ============================ host ============================
extern "C" void kernel_launch(void* const* d_in, const int* in_sizes, int n_in,
                              void* d_out, int out_size, void* d_ws, size_t ws_size,
                              hipStream_t stream) {
    const float* x     = (const float*)d_in[0];
    const int*   ei    = (const int*)d_in[1];
    const float* Wq    = (const float*)d_in[2];
    const float* bq    = (const float*)d_in[3];
    const float* gat_w = (const float*)d_in[4];
    const float* gat_b = (const float*)d_in[5];
    const float* le1_w = (const float*)d_in[6];
    const float* le1_b = (const float*)d_in[7];
    const float* le2_w = (const float*)d_in[8];
    const float* le3_w = (const float*)d_in[9];
    const float* le3_b = (const float*)d_in[10];

    float* xout  = (float*)d_out;          // [K, C]
    float* Ead   = xout + (size_t)KK * CC; // [K, K]
    float* operm = Ead + (size_t)KK * KK;  // [K]

    char* w = (char*)d_ws;
    auto alloc = [&](size_t bytes) -> void* {
        void* p = (void*)w;
        w += (bytes + 255) & ~(size_t)255;
        return p;
    };
    float*  out32  = (float*)alloc((size_t)NN * CC * 4);
    double* beta_node = (double*)alloc(NN * 8);
    double* wv     = (double*)alloc(CC * 8);
    double* consts = (double*)alloc(64);
    int*   lsti_j  = (int*)alloc((size_t)NN * SL * 4);
    int*   slot_ij = (int*)alloc((size_t)NN * SL * 4);
    int*   lstj_i  = (int*)alloc((size_t)NN * SL * 4);
    float* sval_i  = (float*)alloc((size_t)NN * SL * 4);
    float* svalj   = (float*)alloc((size_t)NN * SL * 4);
    int*   n_idx   = (int*)alloc(NN * 4);
    int*   perm    = (int*)alloc(KK * 4);
    int*   deg_i   = (int*)alloc(NN * 4);
    int*   deg_j   = (int*)alloc(NN * 4);

    const int EB = (EE + 255) / 256;  // 272

    k_build<<<EB + CC + NN / 4, 256, 0, stream>>>(ei, lsti_j, slot_ij, lstj_i, x,
                                                  Wq, bq, gat_w, gat_b, wv, consts, beta_node, EB);
    k_attn<<<NN / 4, 256, 0, stream>>>(x, lsti_j, slot_ij, lstj_i,
                                       wv, beta_node, consts,
                                       le1_w, le1_b, le2_w, le3_w, le3_b,
                                       sval_i, svalj, out32, deg_i, deg_j);
    k_rank<<<NN, 256, 0, stream>>>(out32, perm, n_idx, xout, operm);
    k_eadj<<<KK, 256, 0, stream>>>(deg_i, lsti_j, sval_i, deg_j, lstj_i, svalj,
                                   n_idx, perm, Ead);
}